// Round 11
// baseline (336.421 us; speedup 1.0000x reference)
//
#include <hip/hip_runtime.h>

typedef __attribute__((ext_vector_type(4))) float f32x4;
typedef __attribute__((ext_vector_type(8))) short s16x8;
typedef __attribute__((ext_vector_type(4))) short s16x4;
typedef unsigned short u16;

#define NV 8192
#define NE 16384
#define MTOT 24576
#define DD 128
#define HH 256

#define BIGSPLIT 8
#define KRANGE (NE / BIGSPLIT)   // 2048
#define HPITCH 264               // u16 pitch for LDS row buffers (fused MLPs)

// k_big geometry
#define BM2 128
#define KS2 64
#define NST2 (KRANGE / KS2)      // 32
#define AP2 72                   // u16 pitch (64 + 8 pad)
#define ABUFU (BM2 * AP2)
#define BBUFU 8192

// ---------- helpers ----------
__device__ __forceinline__ u16 f2bf(float f) {
    unsigned u = __builtin_bit_cast(unsigned, f);
    u += 0x7fffu + ((u >> 16) & 1u);   // RTNE
    return (u16)(u >> 16);
}

__device__ __forceinline__ s16x8 cvt8(f32x4 v0, f32x4 v1) {
    s16x8 r;
#pragma unroll
    for (int i = 0; i < 4; ++i) { r[i] = (short)f2bf(v0[i]); r[i + 4] = (short)f2bf(v1[i]); }
    return r;
}

// ---------- prep: PE tables + all weight packs ----------
__global__ void k_prep(float* __restrict__ pe1, float* __restrict__ pe2,
                       const float* __restrict__ w11, u16* __restrict__ d11,
                       const float* __restrict__ w12, u16* __restrict__ d12,
                       const float* __restrict__ w21, u16* __restrict__ d21,
                       const float* __restrict__ w22, u16* __restrict__ d22,
                       const float* __restrict__ w31, u16* __restrict__ d31,
                       const float* __restrict__ w32, u16* __restrict__ d32) {
    int b = blockIdx.x, t = threadIdx.x;
    if (b == 0) {
        const float c = logf(10000.0f) / 64.0f;
        for (int idx = t; idx < 9 * DD; idx += 256) {
            int p = idx / DD, col = idx % DD, j = col >> 1;
            float a = (float)p * expf(-(float)j * c);
            pe1[idx] = (col & 1) ? cosf(a) : sinf(a);
        }
        for (int idx = t; idx < 2 * DD; idx += 256) {
            int p = idx / DD, col = idx % DD, j = col >> 1;
            float a = (float)p * expf(-(float)j * c);
            pe2[idx] = (col & 1) ? cosf(a) : sinf(a);
        }
        return;
    }
    b -= 1;
    const float* src; u16* dst; int C, base;
    if (b < 256)      { src = w11; dst = d11; C = 256; base = 0; }
    else if (b < 384) { src = w12; dst = d12; C = 128; base = 256; }
    else if (b < 640) { src = w21; dst = d21; C = 256; base = 384; }
    else if (b < 768) { src = w22; dst = d22; C = 128; base = 640; }
    else if (b < 896) { src = w31; dst = d31; C = 256; base = 768; }
    else              { src = w32; dst = d32; C = 128; base = 896; }
    int i = (b - base) * 256 + t;
    int k = i / C, n = i % C;
    size_t o = (((size_t)(k >> 5) * (C >> 4) + (n >> 4)) * 64 + (n & 15) + (((k & 31) >> 3) << 4)) * 8 + (k & 7);
    dst[o] = f2bf(src[i]);
}

// ---------- LDS-A MLP cores (A rows are wave-private; zero barriers) ----------
template <int K1>
__device__ __forceinline__ void fc1_lds(u16* __restrict__ buf, const u16* __restrict__ W1p,
                                        const float* __restrict__ b1, int lane, int wave) {
    f32x4 acc[16];
#pragma unroll
    for (int nt = 0; nt < 16; ++nt)
#pragma unroll
        for (int j = 0; j < 4; ++j) acc[nt][j] = 0.0f;
    const u16* ap = buf + (size_t)(wave * 16 + (lane & 15)) * HPITCH + ((lane >> 4) << 3);
    const s16x8* bp = (const s16x8*)W1p + lane;
#pragma unroll
    for (int ks = 0; ks < K1 / 32; ++ks) {
        s16x8 a = *(const s16x8*)(ap + ks * 32);
#pragma unroll
        for (int nt = 0; nt < 16; ++nt) {
            s16x8 b = bp[(size_t)(ks * 16 + nt) * 64];
            acc[nt] = __builtin_amdgcn_mfma_f32_16x16x32_bf16(a, b, acc[nt], 0, 0, 0);
        }
    }
    int qg = lane >> 4, cb = lane & 15;
#pragma unroll
    for (int nt = 0; nt < 16; ++nt) {
        int c = nt * 16 + cb;
        float bi = b1[c];
#pragma unroll
        for (int j = 0; j < 4; ++j)
            buf[(size_t)(wave * 16 + qg * 4 + j) * HPITCH + c] = f2bf(fmaxf(acc[nt][j] + bi, 0.0f));
    }
}

__device__ __forceinline__ void fc2_lds(const u16* __restrict__ buf, const u16* __restrict__ W2p,
                                        int lane, int wave, f32x4* acc) {
#pragma unroll
    for (int nt = 0; nt < 8; ++nt)
#pragma unroll
        for (int j = 0; j < 4; ++j) acc[nt][j] = 0.0f;
    const u16* ap = buf + (size_t)(wave * 16 + (lane & 15)) * HPITCH + ((lane >> 4) << 3);
    const s16x8* bp = (const s16x8*)W2p + lane;
#pragma unroll
    for (int ks = 0; ks < 8; ++ks) {
        s16x8 a = *(const s16x8*)(ap + ks * 32);
#pragma unroll
        for (int nt = 0; nt < 8; ++nt) {
            s16x8 b = bp[(size_t)(ks * 8 + nt) * 64];
            acc[nt] = __builtin_amdgcn_mfma_f32_16x16x32_bf16(a, b, acc[nt], 0, 0, 0);
        }
    }
}

// ---------- K2: fused LN1 + concat(PE) + MLP1 (+bpack, +column partials) ----------
__global__ __launch_bounds__(256) void k_fused1(const float* __restrict__ xv, const float* __restrict__ xe,
                                                const int* __restrict__ orders, const float* __restrict__ pe1,
                                                const float* __restrict__ gn, const float* __restrict__ bn,
                                                const u16* __restrict__ W1p, const float* __restrict__ b1v,
                                                const u16* __restrict__ W2p, const float* __restrict__ b2v,
                                                float* __restrict__ xnew, u16* __restrict__ bpack,
                                                float* __restrict__ part) {
    __shared__ u16 buf[64 * HPITCH];
    __shared__ float shsum[4 * 128];
    int t = threadIdx.x, lane = t & 63, wave = t >> 6;
    int qg = lane >> 4, cb = lane & 15;
    int base = blockIdx.x * 64;
    int c8 = cb * 8;
    float g8[8], bn8[8];
#pragma unroll
    for (int i = 0; i < 8; ++i) { g8[i] = gn[c8 + i]; bn8[i] = bn[c8 + i]; }
#pragma unroll
    for (int r4 = 0; r4 < 4; ++r4) {
        int lrow = wave * 16 + r4 * 4 + qg;
        int row = base + lrow;
        bool isE = (row >= NV);
        const float* x = isE ? xe + (size_t)(row - NV) * DD : xv + (size_t)row * DD;
        f32x4 v0 = *(const f32x4*)(x + c8);
        f32x4 v1 = *(const f32x4*)(x + c8 + 4);
        float s1 = 0.0f, s2 = 0.0f;
#pragma unroll
        for (int i = 0; i < 4; ++i) { s1 += v0[i] + v1[i]; s2 += v0[i] * v0[i] + v1[i] * v1[i]; }
#pragma unroll
        for (int o = 1; o < 16; o <<= 1) { s1 += __shfl_xor(s1, o, 64); s2 += __shfl_xor(s2, o, 64); }
        float mu = s1 * (1.0f / DD);
        float var = s2 * (1.0f / DD) - mu * mu;
        float rs = rsqrtf(var + 1e-5f);
        s16x8 o16;
#pragma unroll
        for (int i = 0; i < 4; ++i) {
            o16[i]     = (short)f2bf((v0[i] - mu) * rs * g8[i]     + bn8[i]);
            o16[i + 4] = (short)f2bf((v1[i] - mu) * rs * g8[i + 4] + bn8[i + 4]);
        }
        *(s16x8*)(buf + (size_t)lrow * HPITCH + c8) = o16;
        int ord = isE ? orders[row - NV] : 1;
        const float* pr = pe1 + (size_t)ord * DD + c8;
        f32x4 p0 = *(const f32x4*)pr;
        f32x4 p1 = *(const f32x4*)(pr + 4);
        *(s16x8*)(buf + (size_t)lrow * HPITCH + DD + c8) = cvt8(p0, p1);
    }
    fc1_lds<256>(buf, W1p, b1v, lane, wave);
    f32x4 acc[8];
    fc2_lds(buf, W2p, lane, wave, acc);
    int r0 = base + wave * 16 + qg * 4;
    bool isE = (r0 >= NV);
    int e0 = r0 - NV;
    float colpart[8];
#pragma unroll
    for (int nt = 0; nt < 8; ++nt) {
        int c = nt * 16 + cb;
        float bi = b2v[c];
        float vv[4];
        float cs = 0.0f;
#pragma unroll
        for (int j = 0; j < 4; ++j) {
            int r = r0 + j;
            float res = isE ? xe[(size_t)(r - NV) * DD + c] : xv[(size_t)r * DD + c];
            vv[j] = acc[nt][j] + bi + res;
            xnew[(size_t)r * DD + c] = vv[j];
            cs += vv[j];
        }
        colpart[nt] = cs;
        if (isE) {
            ushort4 p;
            p.x = f2bf(vv[0]); p.y = f2bf(vv[1]); p.z = f2bf(vv[2]); p.w = f2bf(vv[3]);
            size_t o = (((size_t)(e0 >> 5) * 8 + nt) * 64 + cb + (((e0 & 31) >> 3) << 4)) * 8 + (e0 & 7);
            *(ushort4*)(bpack + o) = p;
        }
    }
#pragma unroll
    for (int nt = 0; nt < 8; ++nt) {
        colpart[nt] += __shfl_xor(colpart[nt], 16, 64);
        colpart[nt] += __shfl_xor(colpart[nt], 32, 64);
    }
    if (lane < 16) {
#pragma unroll
        for (int nt = 0; nt < 8; ++nt) shsum[wave * 128 + nt * 16 + lane] = colpart[nt];
    }
    __syncthreads();
    if (t < 128) part[(size_t)blockIdx.x * 128 + t] = shsum[t] + shsum[128 + t] + shsum[256 + t] + shsum[384 + t];
}

// ---------- k_big: 2-deep reg pipeline over dbuf LDS (R9-best, byte-identical) ----------
__global__ __launch_bounds__(256) void k_big(const float* __restrict__ inc, const u16* __restrict__ bpack,
                                             float* __restrict__ yp,
                                             const float* __restrict__ part, const float* __restrict__ pe2,
                                             const float* __restrict__ w1, const float* __restrict__ b1,
                                             const float* __restrict__ w2, const float* __restrict__ b2,
                                             const float* __restrict__ gn, const float* __restrict__ bn,
                                             float* __restrict__ x0n) {
    __shared__ u16 aT[2 * ABUFU];
    __shared__ u16 bT[2 * BBUFU];
    int bid = blockIdx.x;
    if (bid >= 512) {
        __shared__ float x0s[128], cat0[256], h0[256], rs_[128], rq_[128];
        int t = threadIdx.x;
        if (t < 128) {
            float s = 0.0f;
            for (int p = 0; p < MTOT / 64; ++p) s += part[p * 128 + t];
            x0s[t] = s * (1.0f / MTOT);
            rs_[t] = x0s[t];
            rq_[t] = x0s[t] * x0s[t];
        }
        __syncthreads();
        for (int off = 64; off > 0; off >>= 1) {
            if (t < off) { rs_[t] += rs_[t + off]; rq_[t] += rq_[t + off]; }
            __syncthreads();
        }
        float mu0 = rs_[0] * (1.0f / DD);
        float var0 = rq_[0] * (1.0f / DD) - mu0 * mu0;
        float rstd0 = rsqrtf(var0 + 1e-5f);
        if (t < 128) {
            cat0[t] = (x0s[t] - mu0) * rstd0 * gn[t] + bn[t];
            cat0[128 + t] = pe2[t];
        }
        __syncthreads();
        {
            float s = b1[t];
            for (int i = 0; i < 256; ++i) s += cat0[i] * w1[i * 256 + t];
            h0[t] = fmaxf(s, 0.0f);
        }
        __syncthreads();
        if (t < 128) {
            float y = b2[t];
            for (int j = 0; j < 256; ++j) y += h0[j] * w2[j * 128 + t];
            x0n[t] = x0s[t] + y;
        }
        return;
    }
    int t = threadIdx.x, lane = t & 63, w = t >> 6;
    int row0 = (bid & 63) * BM2;
    int split = bid >> 6;
    int kbase = split * KRANGE;

    int frow = w * 32 + (lane & 15);
    int fcol = (lane >> 4) * 8;

    f32x4 stA[8], stB[8];
    s16x8 bstA[4], bstB[4];
    f32x4 acc[2][8];
#pragma unroll
    for (int mt = 0; mt < 2; ++mt)
#pragma unroll
        for (int nt = 0; nt < 8; ++nt)
#pragma unroll
            for (int j = 0; j < 4; ++j) acc[mt][nt][j] = 0.0f;

    int srow4 = w * 32 + (lane >> 4);
    int scol4 = (lane & 15) * 4;
    const float* agp4 = inc + (size_t)(row0 + srow4) * NE + kbase + scol4;

#define ALOAD(st, s) do { \
    const float* p_ = agp4 + (s) * KS2; \
    _Pragma("unroll") \
    for (int j = 0; j < 8; ++j) st[j] = __builtin_nontemporal_load((const f32x4*)(p_ + (size_t)(j * 4) * NE)); } while (0)

#define AWRITE(bsel, st) do { \
    u16* dst_ = aT + (bsel) * ABUFU + (size_t)srow4 * AP2 + scol4; \
    _Pragma("unroll") \
    for (int j = 0; j < 8; ++j) { \
        s16x4 v_; \
        v_[0] = (short)f2bf(st[j][0]); v_[1] = (short)f2bf(st[j][1]); \
        v_[2] = (short)f2bf(st[j][2]); v_[3] = (short)f2bf(st[j][3]); \
        *(s16x4*)(dst_ + (size_t)(j * 4) * AP2) = v_; } } while (0)

#define BLOAD(bst, s) do { \
    const s16x8* src_ = (const s16x8*)bpack + (size_t)(kbase + (s) * KS2) * 16; \
    _Pragma("unroll") \
    for (int c = 0; c < 4; ++c) bst[c] = src_[c * 256 + t]; } while (0)

#define BWRITE(bsel, bst) do { \
    u16* dst_ = bT + (bsel) * BBUFU + t * 8; \
    _Pragma("unroll") \
    for (int c = 0; c < 4; ++c) *(s16x8*)(dst_ + c * 2048) = bst[c]; } while (0)

#define COMPUTE(bsel) do { \
    const u16* ab_ = aT + (bsel) * ABUFU; \
    const u16* bb_ = bT + (bsel) * BBUFU; \
    _Pragma("unroll") \
    for (int kt = 0; kt < 2; ++kt) { \
        s16x8 a0_ = *(const s16x8*)(ab_ + (size_t)frow * AP2 + kt * 32 + fcol); \
        s16x8 a1_ = *(const s16x8*)(ab_ + (size_t)(frow + 16) * AP2 + kt * 32 + fcol); \
        _Pragma("unroll") \
        for (int nt = 0; nt < 8; ++nt) { \
            s16x8 b_ = *(const s16x8*)(bb_ + (size_t)(kt * 8 + nt) * 512 + lane * 8); \
            acc[0][nt] = __builtin_amdgcn_mfma_f32_16x16x32_bf16(a0_, b_, acc[0][nt], 0, 0, 0); \
            acc[1][nt] = __builtin_amdgcn_mfma_f32_16x16x32_bf16(a1_, b_, acc[1][nt], 0, 0, 0); \
        } } } while (0)

    ALOAD(stA, 0); BLOAD(bstA, 0);
    AWRITE(0, stA); BWRITE(0, bstA);
    ALOAD(stB, 1); BLOAD(bstB, 1);
    __syncthreads();

    for (int s = 0; s < NST2; s += 2) {
        COMPUTE(0);
        if (s + 1 < NST2) { AWRITE(1, stB); BWRITE(1, bstB); }
        if (s + 2 < NST2) { ALOAD(stA, s + 2); BLOAD(bstA, s + 2); }
        __syncthreads();
        if (s + 1 < NST2) {
            COMPUTE(1);
            if (s + 2 < NST2) { AWRITE(0, stA); BWRITE(0, bstA); }
            if (s + 3 < NST2) { ALOAD(stB, s + 3); BLOAD(bstB, s + 3); }
            __syncthreads();
        }
    }
#undef ALOAD
#undef AWRITE
#undef BLOAD
#undef BWRITE
#undef COMPUTE

    int rb = row0 + w * 32 + ((lane >> 4) << 2);
    int cb = lane & 15;
#pragma unroll
    for (int mt = 0; mt < 2; ++mt)
#pragma unroll
        for (int nt = 0; nt < 8; ++nt)
#pragma unroll
            for (int j = 0; j < 4; ++j)
                yp[((size_t)split * NV + rb + mt * 16 + j) * DD + nt * 16 + cb] = acc[mt][nt][j];
}

// ---------- K4: fused combine + LN2 + MLP2 + LN3 + MLP3 ----------
__global__ __launch_bounds__(256) void k_fused2(const float* __restrict__ xnew, const float* __restrict__ yp,
                                                const float* __restrict__ suffix, const float* __restrict__ pe2,
                                                const float* __restrict__ g2, const float* __restrict__ b2n,
                                                const u16* __restrict__ W21p, const float* __restrict__ m2b1,
                                                const u16* __restrict__ W22p, const float* __restrict__ m2b2,
                                                const float* __restrict__ x0n,
                                                const float* __restrict__ g3, const float* __restrict__ b3n,
                                                const u16* __restrict__ W31p, const float* __restrict__ m3b1,
                                                const u16* __restrict__ W32p, const float* __restrict__ m3b2,
                                                const float* __restrict__ bb, float* __restrict__ out) {
    __shared__ u16 buf[64 * HPITCH];
    int t = threadIdx.x, lane = t & 63, wave = t >> 6;
    int qg = lane >> 4, cb = lane & 15;
    int base = blockIdx.x * 64;
    int r0l = wave * 16 + qg * 4;
    int r0 = base + r0l;
    float sj[4];
#pragma unroll
    for (int j = 0; j < 4; ++j) sj[j] = 1.0f / (1.0f + suffix[r0 + j]);
    float x1r[8][4];
#pragma unroll
    for (int nt = 0; nt < 8; ++nt) {
        int c = nt * 16 + cb;
#pragma unroll
        for (int j = 0; j < 4; ++j) {
            int row = r0 + j;
            float v = xnew[(size_t)row * DD + c];
#pragma unroll
            for (int s = 0; s < BIGSPLIT; ++s) v += yp[((size_t)s * NV + row) * DD + c];
            x1r[nt][j] = v * sj[j];
        }
    }
    float g2v[8], b2nv[8], pe2v[8], g3v[8], b3nv[8];
#pragma unroll
    for (int nt = 0; nt < 8; ++nt) {
        int c = nt * 16 + cb;
        g2v[nt] = g2[c]; b2nv[nt] = b2n[c];
        pe2v[nt] = pe2[DD + c];
        g3v[nt] = g3[c]; b3nv[nt] = b3n[c];
    }
#pragma unroll
    for (int j = 0; j < 4; ++j) {
        float s1 = 0.0f, s2 = 0.0f;
#pragma unroll
        for (int nt = 0; nt < 8; ++nt) { s1 += x1r[nt][j]; s2 += x1r[nt][j] * x1r[nt][j]; }
#pragma unroll
        for (int o = 1; o < 16; o <<= 1) { s1 += __shfl_xor(s1, o, 64); s2 += __shfl_xor(s2, o, 64); }
        float mu = s1 * (1.0f / DD);
        float var = s2 * (1.0f / DD) - mu * mu;
        float rs = rsqrtf(var + 1e-5f);
        int lrow = r0l + j;
#pragma unroll
        for (int nt = 0; nt < 8; ++nt) {
            int c = nt * 16 + cb;
            buf[(size_t)lrow * HPITCH + c] = f2bf((x1r[nt][j] - mu) * rs * g2v[nt] + b2nv[nt]);
            buf[(size_t)lrow * HPITCH + DD + c] = f2bf(pe2v[nt]);
        }
    }
    fc1_lds<256>(buf, W21p, m2b1, lane, wave);
    f32x4 acc[8];
    fc2_lds(buf, W22p, lane, wave, acc);
    float xmid[8][4];
#pragma unroll
    for (int nt = 0; nt < 8; ++nt) {
        int c = nt * 16 + cb;
        float bi = m2b2[c] + x0n[c];
#pragma unroll
        for (int j = 0; j < 4; ++j) xmid[nt][j] = acc[nt][j] + bi + x1r[nt][j];
    }
#pragma unroll
    for (int j = 0; j < 4; ++j) {
        float s1 = 0.0f, s2 = 0.0f;
#pragma unroll
        for (int nt = 0; nt < 8; ++nt) { s1 += xmid[nt][j]; s2 += xmid[nt][j] * xmid[nt][j]; }
#pragma unroll
        for (int o = 1; o < 16; o <<= 1) { s1 += __shfl_xor(s1, o, 64); s2 += __shfl_xor(s2, o, 64); }
        float mu = s1 * (1.0f / DD);
        float var = s2 * (1.0f / DD) - mu * mu;
        float rs = rsqrtf(var + 1e-5f);
        int lrow = r0l + j;
#pragma unroll
        for (int nt = 0; nt < 8; ++nt) {
            int c = nt * 16 + cb;
            buf[(size_t)lrow * HPITCH + c] = f2bf((xmid[nt][j] - mu) * rs * g3v[nt] + b3nv[nt]);
        }
    }
    fc1_lds<128>(buf, W31p, m3b1, lane, wave);
    fc2_lds(buf, W32p, lane, wave, acc);
#pragma unroll
    for (int nt = 0; nt < 8; ++nt) {
        int c = nt * 16 + cb;
        float bi = m3b2[c] + bb[c];
#pragma unroll
        for (int j = 0; j < 4; ++j)
            out[(size_t)(r0 + j) * DD + c] = acc[nt][j] + bi + xmid[nt][j];
    }
}

// ==================== launch ====================
extern "C" void kernel_launch(void* const* d_in, const int* in_sizes, int n_in,
                              void* d_out, int out_size, void* d_ws, size_t ws_size,
                              hipStream_t stream) {
    const float* x_v    = (const float*)d_in[0];
    const float* x_e    = (const float*)d_in[1];
    const float* inc    = (const float*)d_in[2];
    const float* suffix = (const float*)d_in[3];
    const int*   orders = (const int*)d_in[4];
    const float* m1w1 = (const float*)d_in[5];
    const float* m1b1 = (const float*)d_in[6];
    const float* m1w2 = (const float*)d_in[7];
    const float* m1b2 = (const float*)d_in[8];
    const float* m2w1 = (const float*)d_in[9];
    const float* m2b1 = (const float*)d_in[10];
    const float* m2w2 = (const float*)d_in[11];
    const float* m2b2 = (const float*)d_in[12];
    const float* m3w1 = (const float*)d_in[13];
    const float* m3b1 = (const float*)d_in[14];
    const float* m3w2 = (const float*)d_in[15];
    const float* m3b2 = (const float*)d_in[16];
    const float* g1 = (const float*)d_in[17];
    const float* b1n = (const float*)d_in[18];
    const float* g2 = (const float*)d_in[19];
    const float* b2n = (const float*)d_in[20];
    const float* g3 = (const float*)d_in[21];
    const float* b3n = (const float*)d_in[22];
    const float* bb = (const float*)d_in[23];
    float* out = (float*)d_out;

    char* w = (char*)d_ws;
    float* pe1   = (float*)(w + 0);
    float* pe2   = (float*)(w + 4608);
    float* x0n   = (float*)(w + 5632);
    float* part  = (float*)(w + 6144);
    u16* w11t    = (u16*)(w + 202752);
    u16* w12t    = (u16*)(w + 333824);
    u16* w21t    = (u16*)(w + 399360);
    u16* w22t    = (u16*)(w + 530432);
    u16* w31t    = (u16*)(w + 595968);
    u16* w32t    = (u16*)(w + 661504);
    float* xnew  = (float*)(w + 1048576);
    u16* bpack   = (u16*)(w + 13631488);
    float* yp    = (float*)(w + 17825792);

    // ===== MEASUREMENT ROUND: prep/f1/f2 each launched 3x (idempotent). =====
    // Delta vs 228.1 = 2*(prep+f1+f2) + 6*gap  -> decomposes smalls vs gaps.
    k_prep<<<1025, 256, 0, stream>>>(pe1, pe2, m1w1, w11t, m1w2, w12t,
                                     m2w1, w21t, m2w2, w22t, m3w1, w31t, m3w2, w32t);
    k_prep<<<1025, 256, 0, stream>>>(pe1, pe2, m1w1, w11t, m1w2, w12t,
                                     m2w1, w21t, m2w2, w22t, m3w1, w31t, m3w2, w32t);
    k_prep<<<1025, 256, 0, stream>>>(pe1, pe2, m1w1, w11t, m1w2, w12t,
                                     m2w1, w21t, m2w2, w22t, m3w1, w31t, m3w2, w32t);

    k_fused1<<<MTOT / 64, 256, 0, stream>>>(x_v, x_e, orders, pe1, g1, b1n,
                                            w11t, m1b1, w12t, m1b2, xnew, bpack, part);
    k_fused1<<<MTOT / 64, 256, 0, stream>>>(x_v, x_e, orders, pe1, g1, b1n,
                                            w11t, m1b1, w12t, m1b2, xnew, bpack, part);
    k_fused1<<<MTOT / 64, 256, 0, stream>>>(x_v, x_e, orders, pe1, g1, b1n,
                                            w11t, m1b1, w12t, m1b2, xnew, bpack, part);

    k_big<<<513, 256, 0, stream>>>(inc, bpack, yp,
                                   part, pe2, m2w1, m2b1, m2w2, m2b2, g2, b2n, x0n);

    k_fused2<<<NV / 64, 256, 0, stream>>>(xnew, yp, suffix, pe2, g2, b2n,
                                          w21t, m2b1, w22t, m2b2, x0n,
                                          g3, b3n, w31t, m3b1, w32t, m3b2, bb, out);
    k_fused2<<<NV / 64, 256, 0, stream>>>(xnew, yp, suffix, pe2, g2, b2n,
                                          w21t, m2b1, w22t, m2b2, x0n,
                                          g3, b3n, w31t, m3b1, w32t, m3b2, bb, out);
    k_fused2<<<NV / 64, 256, 0, stream>>>(xnew, yp, suffix, pe2, g2, b2n,
                                          w21t, m2b1, w22t, m2b2, x0n,
                                          g3, b3n, w31t, m3b1, w32t, m3b2, bb, out);
}

// Round 12
// 225.661 us; speedup vs baseline: 1.4908x; 1.4908x over previous
//
#include <hip/hip_runtime.h>

typedef __attribute__((ext_vector_type(4))) float f32x4;
typedef __attribute__((ext_vector_type(8))) short s16x8;
typedef __attribute__((ext_vector_type(4))) short s16x4;
typedef unsigned short u16;

#define NV 8192
#define NE 16384
#define MTOT 24576
#define DD 128
#define HH 256

#define BIGSPLIT 8
#define KRANGE (NE / BIGSPLIT)   // 2048
#define HPITCH 264               // u16 pitch for LDS row buffers (fused MLPs)

// k_big geometry
#define BM2 128
#define KS2 64
#define NST2 (KRANGE / KS2)      // 32
#define AP2 72                   // u16 pitch (64 + 8 pad)
#define ABUFU (BM2 * AP2)
#define BBUFU 8192

// ---------- helpers ----------
__device__ __forceinline__ u16 f2bf(float f) {
    unsigned u = __builtin_bit_cast(unsigned, f);
    u += 0x7fffu + ((u >> 16) & 1u);   // RTNE
    return (u16)(u >> 16);
}

__device__ __forceinline__ s16x8 cvt8(f32x4 v0, f32x4 v1) {
    s16x8 r;
#pragma unroll
    for (int i = 0; i < 4; ++i) { r[i] = (short)f2bf(v0[i]); r[i + 4] = (short)f2bf(v1[i]); }
    return r;
}

// ---------- prep: PE tables + all weight packs ----------
__global__ void k_prep(float* __restrict__ pe1, float* __restrict__ pe2,
                       const float* __restrict__ w11, u16* __restrict__ d11,
                       const float* __restrict__ w12, u16* __restrict__ d12,
                       const float* __restrict__ w21, u16* __restrict__ d21,
                       const float* __restrict__ w22, u16* __restrict__ d22,
                       const float* __restrict__ w31, u16* __restrict__ d31,
                       const float* __restrict__ w32, u16* __restrict__ d32) {
    int b = blockIdx.x, t = threadIdx.x;
    if (b == 0) {
        const float c = logf(10000.0f) / 64.0f;
        for (int idx = t; idx < 9 * DD; idx += 256) {
            int p = idx / DD, col = idx % DD, j = col >> 1;
            float a = (float)p * expf(-(float)j * c);
            pe1[idx] = (col & 1) ? cosf(a) : sinf(a);
        }
        for (int idx = t; idx < 2 * DD; idx += 256) {
            int p = idx / DD, col = idx % DD, j = col >> 1;
            float a = (float)p * expf(-(float)j * c);
            pe2[idx] = (col & 1) ? cosf(a) : sinf(a);
        }
        return;
    }
    b -= 1;
    const float* src; u16* dst; int C, base;
    if (b < 256)      { src = w11; dst = d11; C = 256; base = 0; }
    else if (b < 384) { src = w12; dst = d12; C = 128; base = 256; }
    else if (b < 640) { src = w21; dst = d21; C = 256; base = 384; }
    else if (b < 768) { src = w22; dst = d22; C = 128; base = 640; }
    else if (b < 896) { src = w31; dst = d31; C = 256; base = 768; }
    else              { src = w32; dst = d32; C = 128; base = 896; }
    int i = (b - base) * 256 + t;
    int k = i / C, n = i % C;
    size_t o = (((size_t)(k >> 5) * (C >> 4) + (n >> 4)) * 64 + (n & 15) + (((k & 31) >> 3) << 4)) * 8 + (k & 7);
    dst[o] = f2bf(src[i]);
}

// ---------- LDS-A MLP cores (A rows are wave-private; zero barriers) ----------
template <int K1>
__device__ __forceinline__ void fc1_lds(u16* __restrict__ buf, const u16* __restrict__ W1p,
                                        const float* __restrict__ b1, int lane, int wave) {
    f32x4 acc[16];
#pragma unroll
    for (int nt = 0; nt < 16; ++nt)
#pragma unroll
        for (int j = 0; j < 4; ++j) acc[nt][j] = 0.0f;
    const u16* ap = buf + (size_t)(wave * 16 + (lane & 15)) * HPITCH + ((lane >> 4) << 3);
    const s16x8* bp = (const s16x8*)W1p + lane;
#pragma unroll
    for (int ks = 0; ks < K1 / 32; ++ks) {
        s16x8 a = *(const s16x8*)(ap + ks * 32);
#pragma unroll
        for (int nt = 0; nt < 16; ++nt) {
            s16x8 b = bp[(size_t)(ks * 16 + nt) * 64];
            acc[nt] = __builtin_amdgcn_mfma_f32_16x16x32_bf16(a, b, acc[nt], 0, 0, 0);
        }
    }
    int qg = lane >> 4, cb = lane & 15;
#pragma unroll
    for (int nt = 0; nt < 16; ++nt) {
        int c = nt * 16 + cb;
        float bi = b1[c];
#pragma unroll
        for (int j = 0; j < 4; ++j)
            buf[(size_t)(wave * 16 + qg * 4 + j) * HPITCH + c] = f2bf(fmaxf(acc[nt][j] + bi, 0.0f));
    }
}

__device__ __forceinline__ void fc2_lds(const u16* __restrict__ buf, const u16* __restrict__ W2p,
                                        int lane, int wave, f32x4* acc) {
#pragma unroll
    for (int nt = 0; nt < 8; ++nt)
#pragma unroll
        for (int j = 0; j < 4; ++j) acc[nt][j] = 0.0f;
    const u16* ap = buf + (size_t)(wave * 16 + (lane & 15)) * HPITCH + ((lane >> 4) << 3);
    const s16x8* bp = (const s16x8*)W2p + lane;
#pragma unroll
    for (int ks = 0; ks < 8; ++ks) {
        s16x8 a = *(const s16x8*)(ap + ks * 32);
#pragma unroll
        for (int nt = 0; nt < 8; ++nt) {
            s16x8 b = bp[(size_t)(ks * 8 + nt) * 64];
            acc[nt] = __builtin_amdgcn_mfma_f32_16x16x32_bf16(a, b, acc[nt], 0, 0, 0);
        }
    }
}

// ---------- K2: fused LN1 + concat(PE) + MLP1 (+bpack, +column partials) ----------
__global__ __launch_bounds__(256) void k_fused1(const float* __restrict__ xv, const float* __restrict__ xe,
                                                const int* __restrict__ orders, const float* __restrict__ pe1,
                                                const float* __restrict__ gn, const float* __restrict__ bn,
                                                const u16* __restrict__ W1p, const float* __restrict__ b1v,
                                                const u16* __restrict__ W2p, const float* __restrict__ b2v,
                                                float* __restrict__ xnew, u16* __restrict__ bpack,
                                                float* __restrict__ part) {
    __shared__ u16 buf[64 * HPITCH];
    __shared__ float shsum[4 * 128];
    int t = threadIdx.x, lane = t & 63, wave = t >> 6;
    int qg = lane >> 4, cb = lane & 15;
    int base = blockIdx.x * 64;
    int c8 = cb * 8;
    float g8[8], bn8[8];
#pragma unroll
    for (int i = 0; i < 8; ++i) { g8[i] = gn[c8 + i]; bn8[i] = bn[c8 + i]; }
#pragma unroll
    for (int r4 = 0; r4 < 4; ++r4) {
        int lrow = wave * 16 + r4 * 4 + qg;
        int row = base + lrow;
        bool isE = (row >= NV);
        const float* x = isE ? xe + (size_t)(row - NV) * DD : xv + (size_t)row * DD;
        f32x4 v0 = *(const f32x4*)(x + c8);
        f32x4 v1 = *(const f32x4*)(x + c8 + 4);
        float s1 = 0.0f, s2 = 0.0f;
#pragma unroll
        for (int i = 0; i < 4; ++i) { s1 += v0[i] + v1[i]; s2 += v0[i] * v0[i] + v1[i] * v1[i]; }
#pragma unroll
        for (int o = 1; o < 16; o <<= 1) { s1 += __shfl_xor(s1, o, 64); s2 += __shfl_xor(s2, o, 64); }
        float mu = s1 * (1.0f / DD);
        float var = s2 * (1.0f / DD) - mu * mu;
        float rs = rsqrtf(var + 1e-5f);
        s16x8 o16;
#pragma unroll
        for (int i = 0; i < 4; ++i) {
            o16[i]     = (short)f2bf((v0[i] - mu) * rs * g8[i]     + bn8[i]);
            o16[i + 4] = (short)f2bf((v1[i] - mu) * rs * g8[i + 4] + bn8[i + 4]);
        }
        *(s16x8*)(buf + (size_t)lrow * HPITCH + c8) = o16;
        int ord = isE ? orders[row - NV] : 1;
        const float* pr = pe1 + (size_t)ord * DD + c8;
        f32x4 p0 = *(const f32x4*)pr;
        f32x4 p1 = *(const f32x4*)(pr + 4);
        *(s16x8*)(buf + (size_t)lrow * HPITCH + DD + c8) = cvt8(p0, p1);
    }
    fc1_lds<256>(buf, W1p, b1v, lane, wave);
    f32x4 acc[8];
    fc2_lds(buf, W2p, lane, wave, acc);
    int r0 = base + wave * 16 + qg * 4;
    bool isE = (r0 >= NV);
    int e0 = r0 - NV;
    float colpart[8];
#pragma unroll
    for (int nt = 0; nt < 8; ++nt) {
        int c = nt * 16 + cb;
        float bi = b2v[c];
        float vv[4];
        float cs = 0.0f;
#pragma unroll
        for (int j = 0; j < 4; ++j) {
            int r = r0 + j;
            float res = isE ? xe[(size_t)(r - NV) * DD + c] : xv[(size_t)r * DD + c];
            vv[j] = acc[nt][j] + bi + res;
            xnew[(size_t)r * DD + c] = vv[j];
            cs += vv[j];
        }
        colpart[nt] = cs;
        if (isE) {
            ushort4 p;
            p.x = f2bf(vv[0]); p.y = f2bf(vv[1]); p.z = f2bf(vv[2]); p.w = f2bf(vv[3]);
            size_t o = (((size_t)(e0 >> 5) * 8 + nt) * 64 + cb + (((e0 & 31) >> 3) << 4)) * 8 + (e0 & 7);
            *(ushort4*)(bpack + o) = p;
        }
    }
#pragma unroll
    for (int nt = 0; nt < 8; ++nt) {
        colpart[nt] += __shfl_xor(colpart[nt], 16, 64);
        colpart[nt] += __shfl_xor(colpart[nt], 32, 64);
    }
    if (lane < 16) {
#pragma unroll
        for (int nt = 0; nt < 8; ++nt) shsum[wave * 128 + nt * 16 + lane] = colpart[nt];
    }
    __syncthreads();
    if (t < 128) part[(size_t)blockIdx.x * 128 + t] = shsum[t] + shsum[128 + t] + shsum[256 + t] + shsum[384 + t];
}

// ---------- k_big: R9 structure + counted-vmcnt barriers (loads survive the barrier) ----------
__global__ __launch_bounds__(256) void k_big(const float* __restrict__ inc, const u16* __restrict__ bpack,
                                             float* __restrict__ yp,
                                             const float* __restrict__ part, const float* __restrict__ pe2,
                                             const float* __restrict__ w1, const float* __restrict__ b1,
                                             const float* __restrict__ w2, const float* __restrict__ b2,
                                             const float* __restrict__ gn, const float* __restrict__ bn,
                                             float* __restrict__ x0n) {
    __shared__ u16 aT[2 * ABUFU];
    __shared__ u16 bT[2 * BBUFU];
    int bid = blockIdx.x;
    if (bid >= 512) {
        __shared__ float x0s[128], cat0[256], h0[256], rs_[128], rq_[128];
        int t = threadIdx.x;
        if (t < 128) {
            float s = 0.0f;
            for (int p = 0; p < MTOT / 64; ++p) s += part[p * 128 + t];
            x0s[t] = s * (1.0f / MTOT);
            rs_[t] = x0s[t];
            rq_[t] = x0s[t] * x0s[t];
        }
        __syncthreads();
        for (int off = 64; off > 0; off >>= 1) {
            if (t < off) { rs_[t] += rs_[t + off]; rq_[t] += rq_[t + off]; }
            __syncthreads();
        }
        float mu0 = rs_[0] * (1.0f / DD);
        float var0 = rq_[0] * (1.0f / DD) - mu0 * mu0;
        float rstd0 = rsqrtf(var0 + 1e-5f);
        if (t < 128) {
            cat0[t] = (x0s[t] - mu0) * rstd0 * gn[t] + bn[t];
            cat0[128 + t] = pe2[t];
        }
        __syncthreads();
        {
            float s = b1[t];
            for (int i = 0; i < 256; ++i) s += cat0[i] * w1[i * 256 + t];
            h0[t] = fmaxf(s, 0.0f);
        }
        __syncthreads();
        if (t < 128) {
            float y = b2[t];
            for (int j = 0; j < 256; ++j) y += h0[j] * w2[j * 128 + t];
            x0n[t] = x0s[t] + y;
        }
        return;
    }
    int t = threadIdx.x, lane = t & 63, w = t >> 6;
    int row0 = (bid & 63) * BM2;
    int split = bid >> 6;
    int kbase = split * KRANGE;

    int frow = w * 32 + (lane & 15);
    int fcol = (lane >> 4) * 8;

    f32x4 stA[8], stB[8];
    s16x8 bstA[4], bstB[4];
    f32x4 acc[2][8];
#pragma unroll
    for (int mt = 0; mt < 2; ++mt)
#pragma unroll
        for (int nt = 0; nt < 8; ++nt)
#pragma unroll
            for (int j = 0; j < 4; ++j) acc[mt][nt][j] = 0.0f;

    int srow4 = w * 32 + (lane >> 4);
    int scol4 = (lane & 15) * 4;
    const float* agp4 = inc + (size_t)(row0 + srow4) * NE + kbase + scol4;

// Barrier that does NOT drain vmcnt: LDS ordering needs only lgkmcnt; global loads
// in flight target registers, so they legally survive the barrier (T4 / AITER pattern).
#define BARRIER_KEEP_LOADS() do { \
    asm volatile("s_waitcnt lgkmcnt(0)" ::: "memory"); \
    __builtin_amdgcn_s_barrier(); } while (0)

#define ALOAD(st, s) do { \
    const float* p_ = agp4 + (s) * KS2; \
    _Pragma("unroll") \
    for (int j = 0; j < 8; ++j) st[j] = __builtin_nontemporal_load((const f32x4*)(p_ + (size_t)(j * 4) * NE)); } while (0)

#define AWRITE(bsel, st) do { \
    u16* dst_ = aT + (bsel) * ABUFU + (size_t)srow4 * AP2 + scol4; \
    _Pragma("unroll") \
    for (int j = 0; j < 8; ++j) { \
        s16x4 v_; \
        v_[0] = (short)f2bf(st[j][0]); v_[1] = (short)f2bf(st[j][1]); \
        v_[2] = (short)f2bf(st[j][2]); v_[3] = (short)f2bf(st[j][3]); \
        *(s16x4*)(dst_ + (size_t)(j * 4) * AP2) = v_; } } while (0)

#define BLOAD(bst, s) do { \
    const s16x8* src_ = (const s16x8*)bpack + (size_t)(kbase + (s) * KS2) * 16; \
    _Pragma("unroll") \
    for (int c = 0; c < 4; ++c) bst[c] = src_[c * 256 + t]; } while (0)

#define BWRITE(bsel, bst) do { \
    u16* dst_ = bT + (bsel) * BBUFU + t * 8; \
    _Pragma("unroll") \
    for (int c = 0; c < 4; ++c) *(s16x8*)(dst_ + c * 2048) = bst[c]; } while (0)

#define COMPUTE(bsel) do { \
    const u16* ab_ = aT + (bsel) * ABUFU; \
    const u16* bb_ = bT + (bsel) * BBUFU; \
    _Pragma("unroll") \
    for (int kt = 0; kt < 2; ++kt) { \
        s16x8 a0_ = *(const s16x8*)(ab_ + (size_t)frow * AP2 + kt * 32 + fcol); \
        s16x8 a1_ = *(const s16x8*)(ab_ + (size_t)(frow + 16) * AP2 + kt * 32 + fcol); \
        _Pragma("unroll") \
        for (int nt = 0; nt < 8; ++nt) { \
            s16x8 b_ = *(const s16x8*)(bb_ + (size_t)(kt * 8 + nt) * 512 + lane * 8); \
            acc[0][nt] = __builtin_amdgcn_mfma_f32_16x16x32_bf16(a0_, b_, acc[0][nt], 0, 0, 0); \
            acc[1][nt] = __builtin_amdgcn_mfma_f32_16x16x32_bf16(a1_, b_, acc[1][nt], 0, 0, 0); \
        } } } while (0)

    ALOAD(stA, 0); BLOAD(bstA, 0);
    AWRITE(0, stA); BWRITE(0, bstA);
    ALOAD(stB, 1); BLOAD(bstB, 1);
    BARRIER_KEEP_LOADS();

    for (int s = 0; s < NST2; s += 2) {
        COMPUTE(0);
        if (s + 1 < NST2) { AWRITE(1, stB); BWRITE(1, bstB); }
        if (s + 2 < NST2) { ALOAD(stA, s + 2); BLOAD(bstA, s + 2); }
        BARRIER_KEEP_LOADS();
        if (s + 1 < NST2) {
            COMPUTE(1);
            if (s + 2 < NST2) { AWRITE(0, stA); BWRITE(0, bstA); }
            if (s + 3 < NST2) { ALOAD(stB, s + 3); BLOAD(bstB, s + 3); }
            BARRIER_KEEP_LOADS();
        }
    }
#undef ALOAD
#undef AWRITE
#undef BLOAD
#undef BWRITE
#undef COMPUTE
#undef BARRIER_KEEP_LOADS

    int rb = row0 + w * 32 + ((lane >> 4) << 2);
    int cb = lane & 15;
#pragma unroll
    for (int mt = 0; mt < 2; ++mt)
#pragma unroll
        for (int nt = 0; nt < 8; ++nt)
#pragma unroll
            for (int j = 0; j < 4; ++j)
                yp[((size_t)split * NV + rb + mt * 16 + j) * DD + nt * 16 + cb] = acc[mt][nt][j];
}

// ---------- K4: fused combine + LN2 + MLP2 + LN3 + MLP3 ----------
__global__ __launch_bounds__(256) void k_fused2(const float* __restrict__ xnew, const float* __restrict__ yp,
                                                const float* __restrict__ suffix, const float* __restrict__ pe2,
                                                const float* __restrict__ g2, const float* __restrict__ b2n,
                                                const u16* __restrict__ W21p, const float* __restrict__ m2b1,
                                                const u16* __restrict__ W22p, const float* __restrict__ m2b2,
                                                const float* __restrict__ x0n,
                                                const float* __restrict__ g3, const float* __restrict__ b3n,
                                                const u16* __restrict__ W31p, const float* __restrict__ m3b1,
                                                const u16* __restrict__ W32p, const float* __restrict__ m3b2,
                                                const float* __restrict__ bb, float* __restrict__ out) {
    __shared__ u16 buf[64 * HPITCH];
    int t = threadIdx.x, lane = t & 63, wave = t >> 6;
    int qg = lane >> 4, cb = lane & 15;
    int base = blockIdx.x * 64;
    int r0l = wave * 16 + qg * 4;
    int r0 = base + r0l;
    float sj[4];
#pragma unroll
    for (int j = 0; j < 4; ++j) sj[j] = 1.0f / (1.0f + suffix[r0 + j]);
    float x1r[8][4];
#pragma unroll
    for (int nt = 0; nt < 8; ++nt) {
        int c = nt * 16 + cb;
#pragma unroll
        for (int j = 0; j < 4; ++j) {
            int row = r0 + j;
            float v = xnew[(size_t)row * DD + c];
#pragma unroll
            for (int s = 0; s < BIGSPLIT; ++s) v += yp[((size_t)s * NV + row) * DD + c];
            x1r[nt][j] = v * sj[j];
        }
    }
    float g2v[8], b2nv[8], pe2v[8], g3v[8], b3nv[8];
#pragma unroll
    for (int nt = 0; nt < 8; ++nt) {
        int c = nt * 16 + cb;
        g2v[nt] = g2[c]; b2nv[nt] = b2n[c];
        pe2v[nt] = pe2[DD + c];
        g3v[nt] = g3[c]; b3nv[nt] = b3n[c];
    }
#pragma unroll
    for (int j = 0; j < 4; ++j) {
        float s1 = 0.0f, s2 = 0.0f;
#pragma unroll
        for (int nt = 0; nt < 8; ++nt) { s1 += x1r[nt][j]; s2 += x1r[nt][j] * x1r[nt][j]; }
#pragma unroll
        for (int o = 1; o < 16; o <<= 1) { s1 += __shfl_xor(s1, o, 64); s2 += __shfl_xor(s2, o, 64); }
        float mu = s1 * (1.0f / DD);
        float var = s2 * (1.0f / DD) - mu * mu;
        float rs = rsqrtf(var + 1e-5f);
        int lrow = r0l + j;
#pragma unroll
        for (int nt = 0; nt < 8; ++nt) {
            int c = nt * 16 + cb;
            buf[(size_t)lrow * HPITCH + c] = f2bf((x1r[nt][j] - mu) * rs * g2v[nt] + b2nv[nt]);
            buf[(size_t)lrow * HPITCH + DD + c] = f2bf(pe2v[nt]);
        }
    }
    fc1_lds<256>(buf, W21p, m2b1, lane, wave);
    f32x4 acc[8];
    fc2_lds(buf, W22p, lane, wave, acc);
    float xmid[8][4];
#pragma unroll
    for (int nt = 0; nt < 8; ++nt) {
        int c = nt * 16 + cb;
        float bi = m2b2[c] + x0n[c];
#pragma unroll
        for (int j = 0; j < 4; ++j) xmid[nt][j] = acc[nt][j] + bi + x1r[nt][j];
    }
#pragma unroll
    for (int j = 0; j < 4; ++j) {
        float s1 = 0.0f, s2 = 0.0f;
#pragma unroll
        for (int nt = 0; nt < 8; ++nt) { s1 += xmid[nt][j]; s2 += xmid[nt][j] * xmid[nt][j]; }
#pragma unroll
        for (int o = 1; o < 16; o <<= 1) { s1 += __shfl_xor(s1, o, 64); s2 += __shfl_xor(s2, o, 64); }
        float mu = s1 * (1.0f / DD);
        float var = s2 * (1.0f / DD) - mu * mu;
        float rs = rsqrtf(var + 1e-5f);
        int lrow = r0l + j;
#pragma unroll
        for (int nt = 0; nt < 8; ++nt) {
            int c = nt * 16 + cb;
            buf[(size_t)lrow * HPITCH + c] = f2bf((xmid[nt][j] - mu) * rs * g3v[nt] + b3nv[nt]);
        }
    }
    fc1_lds<128>(buf, W31p, m3b1, lane, wave);
    fc2_lds(buf, W32p, lane, wave, acc);
#pragma unroll
    for (int nt = 0; nt < 8; ++nt) {
        int c = nt * 16 + cb;
        float bi = m3b2[c] + bb[c];
#pragma unroll
        for (int j = 0; j < 4; ++j)
            out[(size_t)(r0 + j) * DD + c] = acc[nt][j] + bi + xmid[nt][j];
    }
}

// ==================== launch ====================
extern "C" void kernel_launch(void* const* d_in, const int* in_sizes, int n_in,
                              void* d_out, int out_size, void* d_ws, size_t ws_size,
                              hipStream_t stream) {
    const float* x_v    = (const float*)d_in[0];
    const float* x_e    = (const float*)d_in[1];
    const float* inc    = (const float*)d_in[2];
    const float* suffix = (const float*)d_in[3];
    const int*   orders = (const int*)d_in[4];
    const float* m1w1 = (const float*)d_in[5];
    const float* m1b1 = (const float*)d_in[6];
    const float* m1w2 = (const float*)d_in[7];
    const float* m1b2 = (const float*)d_in[8];
    const float* m2w1 = (const float*)d_in[9];
    const float* m2b1 = (const float*)d_in[10];
    const float* m2w2 = (const float*)d_in[11];
    const float* m2b2 = (const float*)d_in[12];
    const float* m3w1 = (const float*)d_in[13];
    const float* m3b1 = (const float*)d_in[14];
    const float* m3w2 = (const float*)d_in[15];
    const float* m3b2 = (const float*)d_in[16];
    const float* g1 = (const float*)d_in[17];
    const float* b1n = (const float*)d_in[18];
    const float* g2 = (const float*)d_in[19];
    const float* b2n = (const float*)d_in[20];
    const float* g3 = (const float*)d_in[21];
    const float* b3n = (const float*)d_in[22];
    const float* bb = (const float*)d_in[23];
    float* out = (float*)d_out;

    char* w = (char*)d_ws;
    float* pe1   = (float*)(w + 0);
    float* pe2   = (float*)(w + 4608);
    float* x0n   = (float*)(w + 5632);
    float* part  = (float*)(w + 6144);
    u16* w11t    = (u16*)(w + 202752);
    u16* w12t    = (u16*)(w + 333824);
    u16* w21t    = (u16*)(w + 399360);
    u16* w22t    = (u16*)(w + 530432);
    u16* w31t    = (u16*)(w + 595968);
    u16* w32t    = (u16*)(w + 661504);
    float* xnew  = (float*)(w + 1048576);
    u16* bpack   = (u16*)(w + 13631488);
    float* yp    = (float*)(w + 17825792);

    k_prep<<<1025, 256, 0, stream>>>(pe1, pe2, m1w1, w11t, m1w2, w12t,
                                     m2w1, w21t, m2w2, w22t, m3w1, w31t, m3w2, w32t);

    k_fused1<<<MTOT / 64, 256, 0, stream>>>(x_v, x_e, orders, pe1, g1, b1n,
                                            w11t, m1b1, w12t, m1b2, xnew, bpack, part);

    k_big<<<513, 256, 0, stream>>>(inc, bpack, yp,
                                   part, pe2, m2w1, m2b1, m2w2, m2b2, g2, b2n, x0n);

    k_fused2<<<NV / 64, 256, 0, stream>>>(xnew, yp, suffix, pe2, g2, b2n,
                                          w21t, m2b1, w22t, m2b2, x0n,
                                          g3, b3n, w31t, m3b1, w32t, m3b2, bb, out);
}

// Round 13
// 203.342 us; speedup vs baseline: 1.6545x; 1.1098x over previous
//
#include <hip/hip_runtime.h>

typedef __attribute__((ext_vector_type(4))) float f32x4;
typedef __attribute__((ext_vector_type(8))) short s16x8;
typedef __attribute__((ext_vector_type(4))) short s16x4;
typedef unsigned short u16;

#define NV 8192
#define NE 16384
#define MTOT 24576
#define DD 128
#define HH 256

#define BIGSPLIT 8
#define KRANGE (NE / BIGSPLIT)   // 2048
#define HPITCH 264               // u16 pitch for LDS row buffers (fused MLPs)

// k_big geometry
#define BM2 128
#define KS2 64
#define NST2 (KRANGE / KS2)      // 32
#define AP2 72                   // u16 pitch (64 + 8 pad)
#define ABUFU (BM2 * AP2)
#define BBUFU 8192

// ---------- helpers ----------
__device__ __forceinline__ u16 f2bf(float f) {
    unsigned u = __builtin_bit_cast(unsigned, f);
    u += 0x7fffu + ((u >> 16) & 1u);   // RTNE
    return (u16)(u >> 16);
}

__device__ __forceinline__ s16x8 cvt8(f32x4 v0, f32x4 v1) {
    s16x8 r;
#pragma unroll
    for (int i = 0; i < 4; ++i) { r[i] = (short)f2bf(v0[i]); r[i + 4] = (short)f2bf(v1[i]); }
    return r;
}

// ---------- prep: PE tables + all weight packs ----------
__global__ void k_prep(float* __restrict__ pe1, float* __restrict__ pe2,
                       const float* __restrict__ w11, u16* __restrict__ d11,
                       const float* __restrict__ w12, u16* __restrict__ d12,
                       const float* __restrict__ w21, u16* __restrict__ d21,
                       const float* __restrict__ w22, u16* __restrict__ d22,
                       const float* __restrict__ w31, u16* __restrict__ d31,
                       const float* __restrict__ w32, u16* __restrict__ d32) {
    int b = blockIdx.x, t = threadIdx.x;
    if (b == 0) {
        const float c = logf(10000.0f) / 64.0f;
        for (int idx = t; idx < 9 * DD; idx += 256) {
            int p = idx / DD, col = idx % DD, j = col >> 1;
            float a = (float)p * expf(-(float)j * c);
            pe1[idx] = (col & 1) ? cosf(a) : sinf(a);
        }
        for (int idx = t; idx < 2 * DD; idx += 256) {
            int p = idx / DD, col = idx % DD, j = col >> 1;
            float a = (float)p * expf(-(float)j * c);
            pe2[idx] = (col & 1) ? cosf(a) : sinf(a);
        }
        return;
    }
    b -= 1;
    const float* src; u16* dst; int C, base;
    if (b < 256)      { src = w11; dst = d11; C = 256; base = 0; }
    else if (b < 384) { src = w12; dst = d12; C = 128; base = 256; }
    else if (b < 640) { src = w21; dst = d21; C = 256; base = 384; }
    else if (b < 768) { src = w22; dst = d22; C = 128; base = 640; }
    else if (b < 896) { src = w31; dst = d31; C = 256; base = 768; }
    else              { src = w32; dst = d32; C = 128; base = 896; }
    int i = (b - base) * 256 + t;
    int k = i / C, n = i % C;
    size_t o = (((size_t)(k >> 5) * (C >> 4) + (n >> 4)) * 64 + (n & 15) + (((k & 31) >> 3) << 4)) * 8 + (k & 7);
    dst[o] = f2bf(src[i]);
}

// ---------- LDS-A MLP cores (A rows are wave-private; zero barriers) ----------
template <int K1>
__device__ __forceinline__ void fc1_lds(u16* __restrict__ buf, const u16* __restrict__ W1p,
                                        const float* __restrict__ b1, int lane, int wave) {
    f32x4 acc[16];
#pragma unroll
    for (int nt = 0; nt < 16; ++nt)
#pragma unroll
        for (int j = 0; j < 4; ++j) acc[nt][j] = 0.0f;
    const u16* ap = buf + (size_t)(wave * 16 + (lane & 15)) * HPITCH + ((lane >> 4) << 3);
    const s16x8* bp = (const s16x8*)W1p + lane;
#pragma unroll
    for (int ks = 0; ks < K1 / 32; ++ks) {
        s16x8 a = *(const s16x8*)(ap + ks * 32);
#pragma unroll
        for (int nt = 0; nt < 16; ++nt) {
            s16x8 b = bp[(size_t)(ks * 16 + nt) * 64];
            acc[nt] = __builtin_amdgcn_mfma_f32_16x16x32_bf16(a, b, acc[nt], 0, 0, 0);
        }
    }
    int qg = lane >> 4, cb = lane & 15;
#pragma unroll
    for (int nt = 0; nt < 16; ++nt) {
        int c = nt * 16 + cb;
        float bi = b1[c];
#pragma unroll
        for (int j = 0; j < 4; ++j)
            buf[(size_t)(wave * 16 + qg * 4 + j) * HPITCH + c] = f2bf(fmaxf(acc[nt][j] + bi, 0.0f));
    }
}

__device__ __forceinline__ void fc2_lds(const u16* __restrict__ buf, const u16* __restrict__ W2p,
                                        int lane, int wave, f32x4* acc) {
#pragma unroll
    for (int nt = 0; nt < 8; ++nt)
#pragma unroll
        for (int j = 0; j < 4; ++j) acc[nt][j] = 0.0f;
    const u16* ap = buf + (size_t)(wave * 16 + (lane & 15)) * HPITCH + ((lane >> 4) << 3);
    const s16x8* bp = (const s16x8*)W2p + lane;
#pragma unroll
    for (int ks = 0; ks < 8; ++ks) {
        s16x8 a = *(const s16x8*)(ap + ks * 32);
#pragma unroll
        for (int nt = 0; nt < 8; ++nt) {
            s16x8 b = bp[(size_t)(ks * 8 + nt) * 64];
            acc[nt] = __builtin_amdgcn_mfma_f32_16x16x32_bf16(a, b, acc[nt], 0, 0, 0);
        }
    }
}

// ---------- K2: fused LN1 + concat(PE) + MLP1 (+bpack, +column partials) ----------
__global__ __launch_bounds__(256) void k_fused1(const float* __restrict__ xv, const float* __restrict__ xe,
                                                const int* __restrict__ orders, const float* __restrict__ pe1,
                                                const float* __restrict__ gn, const float* __restrict__ bn,
                                                const u16* __restrict__ W1p, const float* __restrict__ b1v,
                                                const u16* __restrict__ W2p, const float* __restrict__ b2v,
                                                float* __restrict__ xnew, u16* __restrict__ bpack,
                                                float* __restrict__ part) {
    __shared__ u16 buf[64 * HPITCH];
    __shared__ float shsum[4 * 128];
    int t = threadIdx.x, lane = t & 63, wave = t >> 6;
    int qg = lane >> 4, cb = lane & 15;
    int base = blockIdx.x * 64;
    int c8 = cb * 8;
    float g8[8], bn8[8];
#pragma unroll
    for (int i = 0; i < 8; ++i) { g8[i] = gn[c8 + i]; bn8[i] = bn[c8 + i]; }
#pragma unroll
    for (int r4 = 0; r4 < 4; ++r4) {
        int lrow = wave * 16 + r4 * 4 + qg;
        int row = base + lrow;
        bool isE = (row >= NV);
        const float* x = isE ? xe + (size_t)(row - NV) * DD : xv + (size_t)row * DD;
        f32x4 v0 = *(const f32x4*)(x + c8);
        f32x4 v1 = *(const f32x4*)(x + c8 + 4);
        float s1 = 0.0f, s2 = 0.0f;
#pragma unroll
        for (int i = 0; i < 4; ++i) { s1 += v0[i] + v1[i]; s2 += v0[i] * v0[i] + v1[i] * v1[i]; }
#pragma unroll
        for (int o = 1; o < 16; o <<= 1) { s1 += __shfl_xor(s1, o, 64); s2 += __shfl_xor(s2, o, 64); }
        float mu = s1 * (1.0f / DD);
        float var = s2 * (1.0f / DD) - mu * mu;
        float rs = rsqrtf(var + 1e-5f);
        s16x8 o16;
#pragma unroll
        for (int i = 0; i < 4; ++i) {
            o16[i]     = (short)f2bf((v0[i] - mu) * rs * g8[i]     + bn8[i]);
            o16[i + 4] = (short)f2bf((v1[i] - mu) * rs * g8[i + 4] + bn8[i + 4]);
        }
        *(s16x8*)(buf + (size_t)lrow * HPITCH + c8) = o16;
        int ord = isE ? orders[row - NV] : 1;
        const float* pr = pe1 + (size_t)ord * DD + c8;
        f32x4 p0 = *(const f32x4*)pr;
        f32x4 p1 = *(const f32x4*)(pr + 4);
        *(s16x8*)(buf + (size_t)lrow * HPITCH + DD + c8) = cvt8(p0, p1);
    }
    fc1_lds<256>(buf, W1p, b1v, lane, wave);
    f32x4 acc[8];
    fc2_lds(buf, W2p, lane, wave, acc);
    int r0 = base + wave * 16 + qg * 4;
    bool isE = (r0 >= NV);
    int e0 = r0 - NV;
    float colpart[8];
#pragma unroll
    for (int nt = 0; nt < 8; ++nt) {
        int c = nt * 16 + cb;
        float bi = b2v[c];
        float vv[4];
        float cs = 0.0f;
#pragma unroll
        for (int j = 0; j < 4; ++j) {
            int r = r0 + j;
            float res = isE ? xe[(size_t)(r - NV) * DD + c] : xv[(size_t)r * DD + c];
            vv[j] = acc[nt][j] + bi + res;
            xnew[(size_t)r * DD + c] = vv[j];
            cs += vv[j];
        }
        colpart[nt] = cs;
        if (isE) {
            ushort4 p;
            p.x = f2bf(vv[0]); p.y = f2bf(vv[1]); p.z = f2bf(vv[2]); p.w = f2bf(vv[3]);
            size_t o = (((size_t)(e0 >> 5) * 8 + nt) * 64 + cb + (((e0 & 31) >> 3) << 4)) * 8 + (e0 & 7);
            *(ushort4*)(bpack + o) = p;
        }
    }
#pragma unroll
    for (int nt = 0; nt < 8; ++nt) {
        colpart[nt] += __shfl_xor(colpart[nt], 16, 64);
        colpart[nt] += __shfl_xor(colpart[nt], 32, 64);
    }
    if (lane < 16) {
#pragma unroll
        for (int nt = 0; nt < 8; ++nt) shsum[wave * 128 + nt * 16 + lane] = colpart[nt];
    }
    __syncthreads();
    if (t < 128) part[(size_t)blockIdx.x * 128 + t] = shsum[t] + shsum[128 + t] + shsum[256 + t] + shsum[384 + t];
}

// ---------- k_big: R12 structure + per-block chunk-order rotation (DRAM hot-spot breaker) ----------
__global__ __launch_bounds__(256) void k_big(const float* __restrict__ inc, const u16* __restrict__ bpack,
                                             float* __restrict__ yp,
                                             const float* __restrict__ part, const float* __restrict__ pe2,
                                             const float* __restrict__ w1, const float* __restrict__ b1,
                                             const float* __restrict__ w2, const float* __restrict__ b2,
                                             const float* __restrict__ gn, const float* __restrict__ bn,
                                             float* __restrict__ x0n) {
    __shared__ u16 aT[2 * ABUFU];
    __shared__ u16 bT[2 * BBUFU];
    int bid = blockIdx.x;
    if (bid >= 512) {
        __shared__ float x0s[128], cat0[256], h0[256], rs_[128], rq_[128];
        int t = threadIdx.x;
        if (t < 128) {
            float s = 0.0f;
            for (int p = 0; p < MTOT / 64; ++p) s += part[p * 128 + t];
            x0s[t] = s * (1.0f / MTOT);
            rs_[t] = x0s[t];
            rq_[t] = x0s[t] * x0s[t];
        }
        __syncthreads();
        for (int off = 64; off > 0; off >>= 1) {
            if (t < off) { rs_[t] += rs_[t + off]; rq_[t] += rq_[t + off]; }
            __syncthreads();
        }
        float mu0 = rs_[0] * (1.0f / DD);
        float var0 = rq_[0] * (1.0f / DD) - mu0 * mu0;
        float rstd0 = rsqrtf(var0 + 1e-5f);
        if (t < 128) {
            cat0[t] = (x0s[t] - mu0) * rstd0 * gn[t] + bn[t];
            cat0[128 + t] = pe2[t];
        }
        __syncthreads();
        {
            float s = b1[t];
            for (int i = 0; i < 256; ++i) s += cat0[i] * w1[i * 256 + t];
            h0[t] = fmaxf(s, 0.0f);
        }
        __syncthreads();
        if (t < 128) {
            float y = b2[t];
            for (int j = 0; j < 256; ++j) y += h0[j] * w2[j * 128 + t];
            x0n[t] = x0s[t] + y;
        }
        return;
    }
    int t = threadIdx.x, lane = t & 63, w = t >> 6;
    int row0 = (bid & 63) * BM2;
    int split = bid >> 6;
    int kbase = split * KRANGE;
    // Per-block chunk rotation: breaks the device-wide lock-step where every block's
    // step-s reads hit the same 256B-granule residue (row-stride 64KB => channel depends
    // only on chunk index). gcd(7,32)=1 spreads blocks uniformly over all 32 residues.
    const int phase = (bid * 7) & (NST2 - 1);
#define CHUNK(s) (((s) + phase) & (NST2 - 1))

    int frow = w * 32 + (lane & 15);
    int fcol = (lane >> 4) * 8;

    f32x4 stA[8], stB[8];
    s16x8 bstA[4], bstB[4];
    f32x4 acc[2][8];
#pragma unroll
    for (int mt = 0; mt < 2; ++mt)
#pragma unroll
        for (int nt = 0; nt < 8; ++nt)
#pragma unroll
            for (int j = 0; j < 4; ++j) acc[mt][nt][j] = 0.0f;

    int srow4 = w * 32 + (lane >> 4);
    int scol4 = (lane & 15) * 4;
    const float* agp4 = inc + (size_t)(row0 + srow4) * NE + kbase + scol4;

#define BARRIER_KEEP_LOADS() do { \
    asm volatile("s_waitcnt lgkmcnt(0)" ::: "memory"); \
    __builtin_amdgcn_s_barrier(); } while (0)

#define ALOAD(st, s) do { \
    const float* p_ = agp4 + CHUNK(s) * KS2; \
    _Pragma("unroll") \
    for (int j = 0; j < 8; ++j) st[j] = __builtin_nontemporal_load((const f32x4*)(p_ + (size_t)(j * 4) * NE)); } while (0)

#define AWRITE(bsel, st) do { \
    u16* dst_ = aT + (bsel) * ABUFU + (size_t)srow4 * AP2 + scol4; \
    _Pragma("unroll") \
    for (int j = 0; j < 8; ++j) { \
        s16x4 v_; \
        v_[0] = (short)f2bf(st[j][0]); v_[1] = (short)f2bf(st[j][1]); \
        v_[2] = (short)f2bf(st[j][2]); v_[3] = (short)f2bf(st[j][3]); \
        *(s16x4*)(dst_ + (size_t)(j * 4) * AP2) = v_; } } while (0)

#define BLOAD(bst, s) do { \
    const s16x8* src_ = (const s16x8*)bpack + (size_t)(kbase + CHUNK(s) * KS2) * 16; \
    _Pragma("unroll") \
    for (int c = 0; c < 4; ++c) bst[c] = src_[c * 256 + t]; } while (0)

#define BWRITE(bsel, bst) do { \
    u16* dst_ = bT + (bsel) * BBUFU + t * 8; \
    _Pragma("unroll") \
    for (int c = 0; c < 4; ++c) *(s16x8*)(dst_ + c * 2048) = bst[c]; } while (0)

#define COMPUTE(bsel) do { \
    const u16* ab_ = aT + (bsel) * ABUFU; \
    const u16* bb_ = bT + (bsel) * BBUFU; \
    _Pragma("unroll") \
    for (int kt = 0; kt < 2; ++kt) { \
        s16x8 a0_ = *(const s16x8*)(ab_ + (size_t)frow * AP2 + kt * 32 + fcol); \
        s16x8 a1_ = *(const s16x8*)(ab_ + (size_t)(frow + 16) * AP2 + kt * 32 + fcol); \
        _Pragma("unroll") \
        for (int nt = 0; nt < 8; ++nt) { \
            s16x8 b_ = *(const s16x8*)(bb_ + (size_t)(kt * 8 + nt) * 512 + lane * 8); \
            acc[0][nt] = __builtin_amdgcn_mfma_f32_16x16x32_bf16(a0_, b_, acc[0][nt], 0, 0, 0); \
            acc[1][nt] = __builtin_amdgcn_mfma_f32_16x16x32_bf16(a1_, b_, acc[1][nt], 0, 0, 0); \
        } } } while (0)

    ALOAD(stA, 0); BLOAD(bstA, 0);
    AWRITE(0, stA); BWRITE(0, bstA);
    ALOAD(stB, 1); BLOAD(bstB, 1);
    BARRIER_KEEP_LOADS();

    for (int s = 0; s < NST2; s += 2) {
        COMPUTE(0);
        if (s + 1 < NST2) { AWRITE(1, stB); BWRITE(1, bstB); }
        if (s + 2 < NST2) { ALOAD(stA, s + 2); BLOAD(bstA, s + 2); }
        BARRIER_KEEP_LOADS();
        if (s + 1 < NST2) {
            COMPUTE(1);
            if (s + 2 < NST2) { AWRITE(0, stA); BWRITE(0, bstA); }
            if (s + 3 < NST2) { ALOAD(stB, s + 3); BLOAD(bstB, s + 3); }
            BARRIER_KEEP_LOADS();
        }
    }
#undef ALOAD
#undef AWRITE
#undef BLOAD
#undef BWRITE
#undef COMPUTE
#undef BARRIER_KEEP_LOADS
#undef CHUNK

    int rb = row0 + w * 32 + ((lane >> 4) << 2);
    int cb = lane & 15;
#pragma unroll
    for (int mt = 0; mt < 2; ++mt)
#pragma unroll
        for (int nt = 0; nt < 8; ++nt)
#pragma unroll
            for (int j = 0; j < 4; ++j)
                yp[((size_t)split * NV + rb + mt * 16 + j) * DD + nt * 16 + cb] = acc[mt][nt][j];
}

// ---------- K4: fused combine + LN2 + MLP2 + LN3 + MLP3 ----------
__global__ __launch_bounds__(256) void k_fused2(const float* __restrict__ xnew, const float* __restrict__ yp,
                                                const float* __restrict__ suffix, const float* __restrict__ pe2,
                                                const float* __restrict__ g2, const float* __restrict__ b2n,
                                                const u16* __restrict__ W21p, const float* __restrict__ m2b1,
                                                const u16* __restrict__ W22p, const float* __restrict__ m2b2,
                                                const float* __restrict__ x0n,
                                                const float* __restrict__ g3, const float* __restrict__ b3n,
                                                const u16* __restrict__ W31p, const float* __restrict__ m3b1,
                                                const u16* __restrict__ W32p, const float* __restrict__ m3b2,
                                                const float* __restrict__ bb, float* __restrict__ out) {
    __shared__ u16 buf[64 * HPITCH];
    int t = threadIdx.x, lane = t & 63, wave = t >> 6;
    int qg = lane >> 4, cb = lane & 15;
    int base = blockIdx.x * 64;
    int r0l = wave * 16 + qg * 4;
    int r0 = base + r0l;
    float sj[4];
#pragma unroll
    for (int j = 0; j < 4; ++j) sj[j] = 1.0f / (1.0f + suffix[r0 + j]);
    float x1r[8][4];
#pragma unroll
    for (int nt = 0; nt < 8; ++nt) {
        int c = nt * 16 + cb;
#pragma unroll
        for (int j = 0; j < 4; ++j) {
            int row = r0 + j;
            float v = xnew[(size_t)row * DD + c];
#pragma unroll
            for (int s = 0; s < BIGSPLIT; ++s) v += yp[((size_t)s * NV + row) * DD + c];
            x1r[nt][j] = v * sj[j];
        }
    }
    float g2v[8], b2nv[8], pe2v[8], g3v[8], b3nv[8];
#pragma unroll
    for (int nt = 0; nt < 8; ++nt) {
        int c = nt * 16 + cb;
        g2v[nt] = g2[c]; b2nv[nt] = b2n[c];
        pe2v[nt] = pe2[DD + c];
        g3v[nt] = g3[c]; b3nv[nt] = b3n[c];
    }
#pragma unroll
    for (int j = 0; j < 4; ++j) {
        float s1 = 0.0f, s2 = 0.0f;
#pragma unroll
        for (int nt = 0; nt < 8; ++nt) { s1 += x1r[nt][j]; s2 += x1r[nt][j] * x1r[nt][j]; }
#pragma unroll
        for (int o = 1; o < 16; o <<= 1) { s1 += __shfl_xor(s1, o, 64); s2 += __shfl_xor(s2, o, 64); }
        float mu = s1 * (1.0f / DD);
        float var = s2 * (1.0f / DD) - mu * mu;
        float rs = rsqrtf(var + 1e-5f);
        int lrow = r0l + j;
#pragma unroll
        for (int nt = 0; nt < 8; ++nt) {
            int c = nt * 16 + cb;
            buf[(size_t)lrow * HPITCH + c] = f2bf((x1r[nt][j] - mu) * rs * g2v[nt] + b2nv[nt]);
            buf[(size_t)lrow * HPITCH + DD + c] = f2bf(pe2v[nt]);
        }
    }
    fc1_lds<256>(buf, W21p, m2b1, lane, wave);
    f32x4 acc[8];
    fc2_lds(buf, W22p, lane, wave, acc);
    float xmid[8][4];
#pragma unroll
    for (int nt = 0; nt < 8; ++nt) {
        int c = nt * 16 + cb;
        float bi = m2b2[c] + x0n[c];
#pragma unroll
        for (int j = 0; j < 4; ++j) xmid[nt][j] = acc[nt][j] + bi + x1r[nt][j];
    }
#pragma unroll
    for (int j = 0; j < 4; ++j) {
        float s1 = 0.0f, s2 = 0.0f;
#pragma unroll
        for (int nt = 0; nt < 8; ++nt) { s1 += xmid[nt][j]; s2 += xmid[nt][j] * xmid[nt][j]; }
#pragma unroll
        for (int o = 1; o < 16; o <<= 1) { s1 += __shfl_xor(s1, o, 64); s2 += __shfl_xor(s2, o, 64); }
        float mu = s1 * (1.0f / DD);
        float var = s2 * (1.0f / DD) - mu * mu;
        float rs = rsqrtf(var + 1e-5f);
        int lrow = r0l + j;
#pragma unroll
        for (int nt = 0; nt < 8; ++nt) {
            int c = nt * 16 + cb;
            buf[(size_t)lrow * HPITCH + c] = f2bf((xmid[nt][j] - mu) * rs * g3v[nt] + b3nv[nt]);
        }
    }
    fc1_lds<128>(buf, W31p, m3b1, lane, wave);
    fc2_lds(buf, W32p, lane, wave, acc);
#pragma unroll
    for (int nt = 0; nt < 8; ++nt) {
        int c = nt * 16 + cb;
        float bi = m3b2[c] + bb[c];
#pragma unroll
        for (int j = 0; j < 4; ++j)
            out[(size_t)(r0 + j) * DD + c] = acc[nt][j] + bi + xmid[nt][j];
    }
}

// ==================== launch ====================
extern "C" void kernel_launch(void* const* d_in, const int* in_sizes, int n_in,
                              void* d_out, int out_size, void* d_ws, size_t ws_size,
                              hipStream_t stream) {
    const float* x_v    = (const float*)d_in[0];
    const float* x_e    = (const float*)d_in[1];
    const float* inc    = (const float*)d_in[2];
    const float* suffix = (const float*)d_in[3];
    const int*   orders = (const int*)d_in[4];
    const float* m1w1 = (const float*)d_in[5];
    const float* m1b1 = (const float*)d_in[6];
    const float* m1w2 = (const float*)d_in[7];
    const float* m1b2 = (const float*)d_in[8];
    const float* m2w1 = (const float*)d_in[9];
    const float* m2b1 = (const float*)d_in[10];
    const float* m2w2 = (const float*)d_in[11];
    const float* m2b2 = (const float*)d_in[12];
    const float* m3w1 = (const float*)d_in[13];
    const float* m3b1 = (const float*)d_in[14];
    const float* m3w2 = (const float*)d_in[15];
    const float* m3b2 = (const float*)d_in[16];
    const float* g1 = (const float*)d_in[17];
    const float* b1n = (const float*)d_in[18];
    const float* g2 = (const float*)d_in[19];
    const float* b2n = (const float*)d_in[20];
    const float* g3 = (const float*)d_in[21];
    const float* b3n = (const float*)d_in[22];
    const float* bb = (const float*)d_in[23];
    float* out = (float*)d_out;

    char* w = (char*)d_ws;
    float* pe1   = (float*)(w + 0);
    float* pe2   = (float*)(w + 4608);
    float* x0n   = (float*)(w + 5632);
    float* part  = (float*)(w + 6144);
    u16* w11t    = (u16*)(w + 202752);
    u16* w12t    = (u16*)(w + 333824);
    u16* w21t    = (u16*)(w + 399360);
    u16* w22t    = (u16*)(w + 530432);
    u16* w31t    = (u16*)(w + 595968);
    u16* w32t    = (u16*)(w + 661504);
    float* xnew  = (float*)(w + 1048576);
    u16* bpack   = (u16*)(w + 13631488);
    float* yp    = (float*)(w + 17825792);

    k_prep<<<1025, 256, 0, stream>>>(pe1, pe2, m1w1, w11t, m1w2, w12t,
                                     m2w1, w21t, m2w2, w22t, m3w1, w31t, m3w2, w32t);

    k_fused1<<<MTOT / 64, 256, 0, stream>>>(x_v, x_e, orders, pe1, g1, b1n,
                                            w11t, m1b1, w12t, m1b2, xnew, bpack, part);

    k_big<<<513, 256, 0, stream>>>(inc, bpack, yp,
                                   part, pe2, m2w1, m2b1, m2w2, m2b2, g2, b2n, x0n);

    k_fused2<<<NV / 64, 256, 0, stream>>>(xnew, yp, suffix, pe2, g2, b2n,
                                          w21t, m2b1, w22t, m2b2, x0n,
                                          g3, b3n, w31t, m3b1, w32t, m3b2, bb, out);
}